// Round 14
// baseline (1861.881 us; speedup 1.0000x reference)
//
#include <hip/hip_runtime.h>
#include <hip/hip_fp16.h>
#include <cstddef>
#include <cstdint>

#define NB 64
#define TT 1024
#define DD 512
#define HH 512
#define WREG 92   // weight pairs per thread in VGPRs
#define WLDS 36   // weight pairs per k-half in LDS (92+36=128 pairs=256 k)

typedef _Float16 h2_t __attribute__((ext_vector_type(2)));
typedef __attribute__((ext_vector_type(8))) short bf16x8;
typedef __attribute__((ext_vector_type(4))) float f32x4;
typedef __attribute__((ext_vector_type(8))) unsigned short ushort8;

__device__ __forceinline__ float dot2f(uint32_t a, uint32_t b, float c) {
#if __has_builtin(__builtin_amdgcn_fdot2)
    return __builtin_amdgcn_fdot2(__builtin_bit_cast(h2_t, a),
                                  __builtin_bit_cast(h2_t, b), c, false);
#else
    __half2 av = __builtin_bit_cast(__half2, a);
    __half2 bv = __builtin_bit_cast(__half2, b);
    float2 af = __half22float2(av), bf = __half22float2(bv);
    return fmaf(af.x, bf.x, fmaf(af.y, bf.y, c));
#endif
}

// fast tanh: |err| ~1e-7 (validated r5/r8)
__device__ __forceinline__ float fast_tanh(float z) {
    z = fmaxf(-15.f, fminf(15.f, z));
    float u = __builtin_amdgcn_exp2f(-2.885390082f * z);
    return (1.f - u) * __builtin_amdgcn_rcpf(1.f + u);
}

// fp32 -> bf16 bits, round-to-nearest-even
__device__ __forceinline__ unsigned short f2bf(float f) {
    uint32_t u = __builtin_bit_cast(uint32_t, f);
    u += 0x7FFFu + ((u >> 16) & 1u);
    return (unsigned short)(u >> 16);
}

// ---------------------------------------------------------------------------
// Prep: Wt[n][k] = bf16(Wx[k][n])  (tiny, ~5us)
// ---------------------------------------------------------------------------
__global__ void conv_wt(const float* __restrict__ W,
                        unsigned short* __restrict__ Wt) {
    int n = blockIdx.x;
    int kc = threadIdx.x;   // 0..63
    ushort8 o;
#pragma unroll
    for (int i = 0; i < 8; ++i)
        o[i] = f2bf(W[(size_t)(kc * 8 + i) * HH + n]);
    *reinterpret_cast<ushort8*>(&Wt[(size_t)n * DD + kc * 8]) = o;
}

// ---------------------------------------------------------------------------
// Kernel 1: fused MFMA bf16 GEMM (r12-validated; FETCH 70MB, ~85us w/ prep)
// ---------------------------------------------------------------------------
#define GBM 128
#define GBN 128
#define GBK 64
#define LDSW 72

__global__ __launch_bounds__(256, 4) void gemm_bf16f(
    const float* __restrict__ X,            // (M, K) fp32 row-major
    const unsigned short* __restrict__ Bt,  // (N, K) bf16 row-major (= Wx^T)
    const float* __restrict__ bias,
    float* __restrict__ C)                  // (M, H) fp32
{
    __shared__ unsigned short As[GBM * LDSW];
    __shared__ unsigned short Bs[GBN * LDSW];

    const int tid  = threadIdx.x;
    const int m0   = blockIdx.x * GBM;
    const int n0   = blockIdx.y * GBN;
    const int lane = tid & 63;
    const int wave = tid >> 6;
    const int wm   = wave >> 1;
    const int wn   = wave & 1;

    const int axr = tid >> 1;
    const int axc = (tid & 1) * 32;
    const int srow = tid >> 3;
    const int sch  = tid & 7;

    f32x4 acc[4][4] = {};

    const int arow = wm * 64 + (lane & 15);
    const int brow = wn * 64 + (lane & 15);
    const int koff = (lane >> 4) * 8;

    for (int kt = 0; kt < DD / GBK; ++kt) {
        const int k0 = kt * GBK;
        {
            const float* xp = &X[(size_t)(m0 + axr) * DD + k0 + axc];
#pragma unroll
            for (int i = 0; i < 4; ++i) {
                float4 a = *reinterpret_cast<const float4*>(&xp[i * 8]);
                float4 b = *reinterpret_cast<const float4*>(&xp[i * 8 + 4]);
                ushort8 o;
                o[0] = f2bf(a.x); o[1] = f2bf(a.y);
                o[2] = f2bf(a.z); o[3] = f2bf(a.w);
                o[4] = f2bf(b.x); o[5] = f2bf(b.y);
                o[6] = f2bf(b.z); o[7] = f2bf(b.w);
                *reinterpret_cast<ushort8*>(&As[axr * LDSW + axc + i * 8]) = o;
            }
        }
#pragma unroll
        for (int p = 0; p < 4; ++p) {
            const int row = srow + p * 32;
            *reinterpret_cast<ushort8*>(&Bs[row * LDSW + sch * 8]) =
                *reinterpret_cast<const ushort8*>(
                    &Bt[(size_t)(n0 + row) * DD + k0 + sch * 8]);
        }
        __syncthreads();

#pragma unroll
        for (int kk = 0; kk < GBK; kk += 32) {
            bf16x8 af[4], bf[4];
#pragma unroll
            for (int mt = 0; mt < 4; ++mt)
                af[mt] = *reinterpret_cast<const bf16x8*>(
                    &As[(arow + mt * 16) * LDSW + kk + koff]);
#pragma unroll
            for (int nt = 0; nt < 4; ++nt)
                bf[nt] = *reinterpret_cast<const bf16x8*>(
                    &Bs[(brow + nt * 16) * LDSW + kk + koff]);
#pragma unroll
            for (int mt = 0; mt < 4; ++mt)
#pragma unroll
                for (int nt = 0; nt < 4; ++nt)
                    acc[mt][nt] = __builtin_amdgcn_mfma_f32_16x16x32_bf16(
                        af[mt], bf[nt], acc[mt][nt], 0, 0, 0);
        }
        __syncthreads();
    }

#pragma unroll
    for (int nt = 0; nt < 4; ++nt) {
        const int col = n0 + wn * 64 + nt * 16 + (lane & 15);
        const float bv = bias[col];
#pragma unroll
        for (int mt = 0; mt < 4; ++mt) {
            const int rbase = m0 + wm * 64 + mt * 16 + (lane >> 4) * 4;
#pragma unroll
            for (int r = 0; r < 4; ++r)
                C[(size_t)(rbase + r) * HH + col] = acc[mt][nt][r] + bv;
        }
    }
}

// ---------------------------------------------------------------------------
// Kernel 1 (fallback): fp32 VALU GEMM
// ---------------------------------------------------------------------------
#define BM 128
#define BN 128
#define BK 8

__global__ __launch_bounds__(256, 2) void gemm_xw(
    const float* __restrict__ A,
    const float* __restrict__ B,
    const float* __restrict__ bias,
    float* __restrict__ C)
{
    __shared__ float As[BK][BM];
    __shared__ float Bs[BK][BN];

    const int tid  = threadIdx.x;
    const int tm   = tid >> 4;
    const int tn   = tid & 15;
    const int row0 = blockIdx.x * BM;
    const int col0 = blockIdx.y * BN;

    const int ar = tid >> 1;
    const int ac = (tid & 1) * 4;
    const int br = tid >> 5;
    const int bc = (tid & 31) * 4;

    float acc[8][8];
#pragma unroll
    for (int i = 0; i < 8; ++i)
#pragma unroll
        for (int j = 0; j < 8; ++j) acc[i][j] = 0.f;

    for (int k0 = 0; k0 < DD; k0 += BK) {
        float4 av = *reinterpret_cast<const float4*>(
            &A[(size_t)(row0 + ar) * DD + k0 + ac]);
        float4 bv = *reinterpret_cast<const float4*>(
            &B[(size_t)(k0 + br) * HH + col0 + bc]);

        As[ac + 0][ar] = av.x;
        As[ac + 1][ar] = av.y;
        As[ac + 2][ar] = av.z;
        As[ac + 3][ar] = av.w;
        *reinterpret_cast<float4*>(&Bs[br][bc]) = bv;
        __syncthreads();

#pragma unroll
        for (int kk = 0; kk < BK; ++kk) {
            float a[8], b[8];
            *reinterpret_cast<float4*>(&a[0]) =
                *reinterpret_cast<const float4*>(&As[kk][tm * 8]);
            *reinterpret_cast<float4*>(&a[4]) =
                *reinterpret_cast<const float4*>(&As[kk][tm * 8 + 4]);
            *reinterpret_cast<float4*>(&b[0]) =
                *reinterpret_cast<const float4*>(&Bs[kk][tn * 8]);
            *reinterpret_cast<float4*>(&b[4]) =
                *reinterpret_cast<const float4*>(&Bs[kk][tn * 8 + 4]);
#pragma unroll
            for (int i = 0; i < 8; ++i)
#pragma unroll
                for (int j = 0; j < 8; ++j)
                    acc[i][j] = fmaf(a[i], b[j], acc[i][j]);
        }
        __syncthreads();
    }

#pragma unroll
    for (int i = 0; i < 8; ++i) {
        const int row = row0 + tm * 8 + i;
#pragma unroll
        for (int j = 0; j < 8; j += 4) {
            const int col = col0 + tn * 8 + j;
            float4 o;
            o.x = acc[i][j + 0] + bias[col + 0];
            o.y = acc[i][j + 1] + bias[col + 1];
            o.z = acc[i][j + 2] + bias[col + 2];
            o.w = acc[i][j + 3] + bias[col + 3];
            *reinterpret_cast<float4*>(&C[(size_t)row * HH + col]) = o;
        }
    }
}

// ---------------------------------------------------------------------------
// Kernel 2: WHOLE-BATCH-PER-BLOCK scan. 64 blocks x 1024 threads.
// Thread (j = tid&511, half = tid>>9) owns column j's k-half: 128 packed
// fp16 pairs = 92 in VGPRs (w[WREG]) + 36 in LDS (Wl, 144KB).
// All 512x512 weights are CU-resident -> ZERO cross-block traffic/sync.
// Per step: 128 dot2/thread (h reads are wave-uniform LDS broadcasts,
// conflict-free) -> partial[half][j] -> B1 -> 512 producers sum 2 halves
// + xw, tanh, write out + packed hp[nxt] -> B2. Deterministic, no
// atomics, no workspace, trivially graph-replay-safe.
// LDS: Wl 144KB + hp 2KB + partial 4KB = 150KB (<=160KB/CU).
// VGPR: 92 weights + ~30 working <= 128 cap (16 waves, bounds(1024,4)).
// ---------------------------------------------------------------------------
__global__ __launch_bounds__(1024, 4) void rnn_scan_reg(
    const float* __restrict__ Wh,    // (H, H) fp32 row-major
    const float* __restrict__ h0,    // (N, H)
    float* __restrict__ out)         // (N, T, H): in = xw, out = h
{
    __shared__ uint32_t Wl[2][9][HH][4];              // 144 KB
    __shared__ __align__(16) uint32_t hp[2][HH / 2];  // 2 KB packed half2 h
    __shared__ float partial[2][HH];                  // 4 KB

    const int tid  = threadIdx.x;
    const int j    = tid & (HH - 1);
    const int half = tid >> 9;
    const int n    = blockIdx.x;

    // ---- one-time: 92 weight pairs -> VGPRs (coalesced in j) ----
    uint32_t w[WREG];
    {
        const float* wc = Wh + (size_t)(half * 256) * HH + j;
#pragma unroll
        for (int p = 0; p < WREG; ++p) {
            float e0 = wc[(size_t)(2 * p) * HH];
            float e1 = wc[(size_t)(2 * p + 1) * HH];
            w[p] = __builtin_bit_cast(uint32_t, __floats2half2_rn(e0, e1));
        }
    }
    // ---- one-time: 36 pairs/half -> LDS (entries: hf,lg,e per column) ----
    for (int idx = tid; idx < 2 * 9 * 4 * HH; idx += 1024) {
        int jj  = idx & (HH - 1);
        int e   = (idx >> 9) & 3;
        int rem = idx >> 11;          // 0..17
        int lg  = rem % 9;
        int hf  = rem / 9;
        int k2  = hf * 128 + WREG + 4 * lg + e;
        float e0 = Wh[(size_t)(2 * k2) * HH + jj];
        float e1 = Wh[(size_t)(2 * k2 + 1) * HH + jj];
        Wl[hf][lg][jj][e] =
            __builtin_bit_cast(uint32_t, __floats2half2_rn(e0, e1));
    }

    if (tid < HH)
        ((__half*)hp[0])[tid] = __float2half(h0[(size_t)n * HH + tid]);
    __syncthreads();

    float* outn = out + (size_t)n * TT * HH;

    int cur = 0;
    for (int t = 0; t < TT; ++t) {
        // prefetch xw (producers only; consumed after B1)
        float xw = 0.f;
        if (tid < HH) xw = outn[(size_t)t * HH + tid];

        // 128 dot2: pairs [half*128, half*128+128)
        const uint4* hpw = (const uint4*)&hp[cur][half * 128];
        float a0 = 0.f, a1 = 0.f, a2 = 0.f, a3 = 0.f;
#pragma unroll
        for (int q = 0; q < 23; ++q) {          // register pairs 0..91
            uint4 hv = hpw[q];
            a0 = dot2f(hv.x, w[4 * q + 0], a0);
            a1 = dot2f(hv.y, w[4 * q + 1], a1);
            a2 = dot2f(hv.z, w[4 * q + 2], a2);
            a3 = dot2f(hv.w, w[4 * q + 3], a3);
        }
#pragma unroll
        for (int lg = 0; lg < 9; ++lg) {        // LDS pairs 92..127
            uint4 hv = hpw[23 + lg];
            uint4 wl = *(const uint4*)&Wl[half][lg][j][0];
            a0 = dot2f(hv.x, wl.x, a0);
            a1 = dot2f(hv.y, wl.y, a1);
            a2 = dot2f(hv.z, wl.z, a2);
            a3 = dot2f(hv.w, wl.w, a3);
        }
        partial[half][j] = (a0 + a1) + (a2 + a3);
        __syncthreads();                                     // B1

        if (tid < HH) {
            float z = partial[0][tid] + partial[1][tid] + xw;
            float h = fast_tanh(z);
            outn[(size_t)t * HH + tid] = h;
            ((__half*)hp[cur ^ 1])[tid] = __float2half(h);
        }
        __syncthreads();                                     // B2
        cur ^= 1;
    }
}

// ---------------------------------------------------------------------------
extern "C" void kernel_launch(void* const* d_in, const int* in_sizes, int n_in,
                              void* d_out, int out_size, void* d_ws, size_t ws_size,
                              hipStream_t stream) {
    const float* x  = (const float*)d_in[0];   // (N, T, D)
    const float* h0 = (const float*)d_in[1];   // (N, H)
    const float* Wx = (const float*)d_in[2];   // (D, H)
    const float* Wh = (const float*)d_in[3];   // (H, H)
    const float* b  = (const float*)d_in[4];   // (H)
    float* out = (float*)d_out;                // (N, T, H)

    const long   M    = (long)NB * TT;         // 65536
    const size_t wt_b = (size_t)HH * DD * 2;   // 512 KB

    if (ws_size >= wt_b) {
        unsigned short* Wt = (unsigned short*)d_ws;
        conv_wt<<<HH, 64, 0, stream>>>(Wx, Wt);
        dim3 gg(M / GBM, HH / GBN);
        gemm_bf16f<<<gg, 256, 0, stream>>>(x, Wt, b, out);
    } else {
        dim3 g1(M / BM, HH / BN);
        gemm_xw<<<g1, 256, 0, stream>>>(x, Wx, b, out);
    }
    rnn_scan_reg<<<NB, 1024, 0, stream>>>(Wh, h0, out);
}

// Round 15
// 1746.529 us; speedup vs baseline: 1.0660x; 1.0660x over previous
//
#include <hip/hip_runtime.h>
#include <hip/hip_fp16.h>
#include <cstddef>
#include <cstdint>

#define NB 64
#define TT 1024
#define DD 512
#define HH 512
#define RP 28   // register-resident weight pairs per column per thread
#define LP 4    // LDS-resident weight pairs per column (RP+LP=32 = 64 k)

typedef _Float16 h2_t __attribute__((ext_vector_type(2)));
typedef __attribute__((ext_vector_type(8))) short bf16x8;
typedef __attribute__((ext_vector_type(4))) float f32x4;
typedef __attribute__((ext_vector_type(8))) unsigned short ushort8;

__device__ __forceinline__ float dot2f(uint32_t a, uint32_t b, float c) {
#if __has_builtin(__builtin_amdgcn_fdot2)
    return __builtin_amdgcn_fdot2(__builtin_bit_cast(h2_t, a),
                                  __builtin_bit_cast(h2_t, b), c, false);
#else
    __half2 av = __builtin_bit_cast(__half2, a);
    __half2 bv = __builtin_bit_cast(__half2, b);
    float2 af = __half22float2(av), bf = __half22float2(bv);
    return fmaf(af.x, bf.x, fmaf(af.y, bf.y, c));
#endif
}

// fast tanh: |err| ~1e-7 (validated r5/r8)
__device__ __forceinline__ float fast_tanh(float z) {
    z = fmaxf(-15.f, fminf(15.f, z));
    float u = __builtin_amdgcn_exp2f(-2.885390082f * z);
    return (1.f - u) * __builtin_amdgcn_rcpf(1.f + u);
}

// fp32 -> bf16 bits, round-to-nearest-even
__device__ __forceinline__ unsigned short f2bf(float f) {
    uint32_t u = __builtin_bit_cast(uint32_t, f);
    u += 0x7FFFu + ((u >> 16) & 1u);
    return (unsigned short)(u >> 16);
}

// ---------------------------------------------------------------------------
// Prep: Wt[n][k] = bf16(Wx[k][n])  (tiny, ~5us)
// ---------------------------------------------------------------------------
__global__ void conv_wt(const float* __restrict__ W,
                        unsigned short* __restrict__ Wt) {
    int n = blockIdx.x;
    int kc = threadIdx.x;   // 0..63
    ushort8 o;
#pragma unroll
    for (int i = 0; i < 8; ++i)
        o[i] = f2bf(W[(size_t)(kc * 8 + i) * HH + n]);
    *reinterpret_cast<ushort8*>(&Wt[(size_t)n * DD + kc * 8]) = o;
}

// ---------------------------------------------------------------------------
// Kernel 1: fused MFMA bf16 GEMM (r12-validated; FETCH 70MB, ~85us w/ prep)
// ---------------------------------------------------------------------------
#define GBM 128
#define GBN 128
#define GBK 64
#define LDSW 72

__global__ __launch_bounds__(256, 4) void gemm_bf16f(
    const float* __restrict__ X,            // (M, K) fp32 row-major
    const unsigned short* __restrict__ Bt,  // (N, K) bf16 row-major (= Wx^T)
    const float* __restrict__ bias,
    float* __restrict__ C)                  // (M, H) fp32
{
    __shared__ unsigned short As[GBM * LDSW];
    __shared__ unsigned short Bs[GBN * LDSW];

    const int tid  = threadIdx.x;
    const int m0   = blockIdx.x * GBM;
    const int n0   = blockIdx.y * GBN;
    const int lane = tid & 63;
    const int wave = tid >> 6;
    const int wm   = wave >> 1;
    const int wn   = wave & 1;

    const int axr = tid >> 1;
    const int axc = (tid & 1) * 32;
    const int srow = tid >> 3;
    const int sch  = tid & 7;

    f32x4 acc[4][4] = {};

    const int arow = wm * 64 + (lane & 15);
    const int brow = wn * 64 + (lane & 15);
    const int koff = (lane >> 4) * 8;

    for (int kt = 0; kt < DD / GBK; ++kt) {
        const int k0 = kt * GBK;
        {
            const float* xp = &X[(size_t)(m0 + axr) * DD + k0 + axc];
#pragma unroll
            for (int i = 0; i < 4; ++i) {
                float4 a = *reinterpret_cast<const float4*>(&xp[i * 8]);
                float4 b = *reinterpret_cast<const float4*>(&xp[i * 8 + 4]);
                ushort8 o;
                o[0] = f2bf(a.x); o[1] = f2bf(a.y);
                o[2] = f2bf(a.z); o[3] = f2bf(a.w);
                o[4] = f2bf(b.x); o[5] = f2bf(b.y);
                o[6] = f2bf(b.z); o[7] = f2bf(b.w);
                *reinterpret_cast<ushort8*>(&As[axr * LDSW + axc + i * 8]) = o;
            }
        }
#pragma unroll
        for (int p = 0; p < 4; ++p) {
            const int row = srow + p * 32;
            *reinterpret_cast<ushort8*>(&Bs[row * LDSW + sch * 8]) =
                *reinterpret_cast<const ushort8*>(
                    &Bt[(size_t)(n0 + row) * DD + k0 + sch * 8]);
        }
        __syncthreads();

#pragma unroll
        for (int kk = 0; kk < GBK; kk += 32) {
            bf16x8 af[4], bf[4];
#pragma unroll
            for (int mt = 0; mt < 4; ++mt)
                af[mt] = *reinterpret_cast<const bf16x8*>(
                    &As[(arow + mt * 16) * LDSW + kk + koff]);
#pragma unroll
            for (int nt = 0; nt < 4; ++nt)
                bf[nt] = *reinterpret_cast<const bf16x8*>(
                    &Bs[(brow + nt * 16) * LDSW + kk + koff]);
#pragma unroll
            for (int mt = 0; mt < 4; ++mt)
#pragma unroll
                for (int nt = 0; nt < 4; ++nt)
                    acc[mt][nt] = __builtin_amdgcn_mfma_f32_16x16x32_bf16(
                        af[mt], bf[nt], acc[mt][nt], 0, 0, 0);
        }
        __syncthreads();
    }

#pragma unroll
    for (int nt = 0; nt < 4; ++nt) {
        const int col = n0 + wn * 64 + nt * 16 + (lane & 15);
        const float bv = bias[col];
#pragma unroll
        for (int mt = 0; mt < 4; ++mt) {
            const int rbase = m0 + wm * 64 + mt * 16 + (lane >> 4) * 4;
#pragma unroll
            for (int r = 0; r < 4; ++r)
                C[(size_t)(rbase + r) * HH + col] = acc[mt][nt][r] + bv;
        }
    }
}

// ---------------------------------------------------------------------------
// Kernel 1 (fallback): fp32 VALU GEMM
// ---------------------------------------------------------------------------
#define BM 128
#define BN 128
#define BK 8

__global__ __launch_bounds__(256, 2) void gemm_xw(
    const float* __restrict__ A,
    const float* __restrict__ B,
    const float* __restrict__ bias,
    float* __restrict__ C)
{
    __shared__ float As[BK][BM];
    __shared__ float Bs[BK][BN];

    const int tid  = threadIdx.x;
    const int tm   = tid >> 4;
    const int tn   = tid & 15;
    const int row0 = blockIdx.x * BM;
    const int col0 = blockIdx.y * BN;

    const int ar = tid >> 1;
    const int ac = (tid & 1) * 4;
    const int br = tid >> 5;
    const int bc = (tid & 31) * 4;

    float acc[8][8];
#pragma unroll
    for (int i = 0; i < 8; ++i)
#pragma unroll
        for (int j = 0; j < 8; ++j) acc[i][j] = 0.f;

    for (int k0 = 0; k0 < DD; k0 += BK) {
        float4 av = *reinterpret_cast<const float4*>(
            &A[(size_t)(row0 + ar) * DD + k0 + ac]);
        float4 bv = *reinterpret_cast<const float4*>(
            &B[(size_t)(k0 + br) * HH + col0 + bc]);

        As[ac + 0][ar] = av.x;
        As[ac + 1][ar] = av.y;
        As[ac + 2][ar] = av.z;
        As[ac + 3][ar] = av.w;
        *reinterpret_cast<float4*>(&Bs[br][bc]) = bv;
        __syncthreads();

#pragma unroll
        for (int kk = 0; kk < BK; ++kk) {
            float a[8], b[8];
            *reinterpret_cast<float4*>(&a[0]) =
                *reinterpret_cast<const float4*>(&As[kk][tm * 8]);
            *reinterpret_cast<float4*>(&a[4]) =
                *reinterpret_cast<const float4*>(&As[kk][tm * 8 + 4]);
            *reinterpret_cast<float4*>(&b[0]) =
                *reinterpret_cast<const float4*>(&Bs[kk][tn * 8]);
            *reinterpret_cast<float4*>(&b[4]) =
                *reinterpret_cast<const float4*>(&Bs[kk][tn * 8 + 4]);
#pragma unroll
            for (int i = 0; i < 8; ++i)
#pragma unroll
                for (int j = 0; j < 8; ++j)
                    acc[i][j] = fmaf(a[i], b[j], acc[i][j]);
        }
        __syncthreads();
    }

#pragma unroll
    for (int i = 0; i < 8; ++i) {
        const int row = row0 + tm * 8 + i;
#pragma unroll
        for (int j = 0; j < 8; j += 4) {
            const int col = col0 + tn * 8 + j;
            float4 o;
            o.x = acc[i][j + 0] + bias[col + 0];
            o.y = acc[i][j + 1] + bias[col + 1];
            o.z = acc[i][j + 2] + bias[col + 2];
            o.w = acc[i][j + 3] + bias[col + 3];
            *reinterpret_cast<float4*>(&C[(size_t)row * HH + col]) = o;
        }
    }
}

// ---------------------------------------------------------------------------
// Kernel 2: WHOLE-BATCH-PER-BLOCK scan v2 — LDS-traffic-minimizing split.
// 64 blocks x 512 threads (8 waves -> 256-reg cap). Thread (cg=tid&63,
// ks=tid>>6) owns columns [cg*8, cg*8+8) over k in [ks*64, ks*64+64):
// 32 pairs/col = 28 in registers (224 regs) + 4 in LDS (Wl, 64KB).
// Per step per CU (cycle model, validated against r14's 4180cy):
//   hp broadcasts: 8 uint4/thread, wave-uniform -> 64 instr ~260cy
//   Wl per-lane uint4 reads: 8/thread -> 64 x 12cy = 770cy
//   partial: uint4 writes (2-way alias, free) + b32 reads ~580cy
//   VALU: 256 dot2 x 2cy x 2 waves/SIMD = 1024cy (overlaps LDS pipe)
//   => step ~2000-2400cy. ZERO cross-block sync, no atomics, replay-safe.
// LDS: Wl 64KB + hp 2KB + partial 16KB = 82KB (1 block/CU).
// ---------------------------------------------------------------------------
__global__ __launch_bounds__(512, 2) void rnn_scan_wb(
    const float* __restrict__ Wh,    // (H, H) fp32 row-major
    const float* __restrict__ h0,    // (N, H)
    float* __restrict__ out)         // (N, T, H): in = xw, out = h
{
    __shared__ uint32_t Wl[8][LP][HH];                // [ks][lg][col] 64KB
    __shared__ __align__(16) uint32_t hp[2][HH / 2];  // packed half2 h, 2KB
    __shared__ float partial[8][HH];                  // [ks][col] 16KB

    const int tid = threadIdx.x;
    const int cg  = tid & 63;
    const int ks  = tid >> 6;         // 0..7
    const int c0  = cg << 3;          // column base (8 cols/thread)
    const int n   = blockIdx.x;

    // ---- one-time: register weights wreg[col][pair], 8x28 = 224 regs ----
    uint32_t wreg[8][RP];
    {
        const float* wb = Wh + (size_t)(ks * 64) * HH + c0;
#pragma unroll
        for (int p = 0; p < RP; ++p) {
            const float* r0 = wb + (size_t)(2 * p) * HH;
            const float* r1 = wb + (size_t)(2 * p + 1) * HH;
            float4 a0 = *reinterpret_cast<const float4*>(r0);
            float4 a1 = *reinterpret_cast<const float4*>(r0 + 4);
            float4 b0 = *reinterpret_cast<const float4*>(r1);
            float4 b1 = *reinterpret_cast<const float4*>(r1 + 4);
            wreg[0][p] = __builtin_bit_cast(uint32_t, __floats2half2_rn(a0.x, b0.x));
            wreg[1][p] = __builtin_bit_cast(uint32_t, __floats2half2_rn(a0.y, b0.y));
            wreg[2][p] = __builtin_bit_cast(uint32_t, __floats2half2_rn(a0.z, b0.z));
            wreg[3][p] = __builtin_bit_cast(uint32_t, __floats2half2_rn(a0.w, b0.w));
            wreg[4][p] = __builtin_bit_cast(uint32_t, __floats2half2_rn(a1.x, b1.x));
            wreg[5][p] = __builtin_bit_cast(uint32_t, __floats2half2_rn(a1.y, b1.y));
            wreg[6][p] = __builtin_bit_cast(uint32_t, __floats2half2_rn(a1.z, b1.z));
            wreg[7][p] = __builtin_bit_cast(uint32_t, __floats2half2_rn(a1.w, b1.w));
        }
    }
    // ---- one-time: LDS weights (pairs RP..31 of each ks, all cols) ----
    for (int idx = tid; idx < 8 * LP * HH; idx += 512) {
        int col = idx & (HH - 1);
        int rem = idx >> 9;           // 0..31
        int lg  = rem & (LP - 1);
        int ksx = rem >> 2;
        int k2  = ksx * 32 + RP + lg;
        float e0 = Wh[(size_t)(2 * k2) * HH + col];
        float e1 = Wh[(size_t)(2 * k2 + 1) * HH + col];
        Wl[ksx][lg][col] =
            __builtin_bit_cast(uint32_t, __floats2half2_rn(e0, e1));
    }

    ((__half*)hp[0])[tid] = __float2half(h0[(size_t)n * HH + tid]);
    __syncthreads();

    float* outn = out + (size_t)n * TT * HH;

    int cur = 0;
    for (int t = 0; t < TT; ++t) {
        // prefetch xw for own reduce column (= tid); consumed after B1
        float xw = outn[(size_t)t * HH + tid];

        const uint4* hpw = (const uint4*)&hp[cur][ks * 32]; // 8 uint4, bcast
        float acc[8] = {0.f, 0.f, 0.f, 0.f, 0.f, 0.f, 0.f, 0.f};

        // register pairs 0..27 (q = 0..6)
#pragma unroll
        for (int q = 0; q < 7; ++q) {
            uint4 hv = hpw[q];
#pragma unroll
            for (int i = 0; i < 8; ++i) {
                acc[i] = dot2f(hv.x, wreg[i][4 * q + 0], acc[i]);
                acc[i] = dot2f(hv.y, wreg[i][4 * q + 1], acc[i]);
                acc[i] = dot2f(hv.z, wreg[i][4 * q + 2], acc[i]);
                acc[i] = dot2f(hv.w, wreg[i][4 * q + 3], acc[i]);
            }
        }
        // LDS pairs 28..31 (q = 7): wl[lg] covers 4 cols each
        {
            uint4 hv = hpw[7];
            uint4 wl0[LP], wl1[LP];
#pragma unroll
            for (int lg = 0; lg < LP; ++lg) {
                wl0[lg] = *(const uint4*)&Wl[ks][lg][c0];
                wl1[lg] = *(const uint4*)&Wl[ks][lg][c0 + 4];
            }
#pragma unroll
            for (int i = 0; i < 4; ++i) {
                acc[i] = dot2f(hv.x, wl0[0][i], acc[i]);
                acc[i] = dot2f(hv.y, wl0[1][i], acc[i]);
                acc[i] = dot2f(hv.z, wl0[2][i], acc[i]);
                acc[i] = dot2f(hv.w, wl0[3][i], acc[i]);
            }
#pragma unroll
            for (int i = 0; i < 4; ++i) {
                acc[4 + i] = dot2f(hv.x, wl1[0][i], acc[4 + i]);
                acc[4 + i] = dot2f(hv.y, wl1[1][i], acc[4 + i]);
                acc[4 + i] = dot2f(hv.z, wl1[2][i], acc[4 + i]);
                acc[4 + i] = dot2f(hv.w, wl1[3][i], acc[4 + i]);
            }
        }

        // write partials: two uint4 per thread (lane stride 32B -> 2-way, free)
        *reinterpret_cast<f32x4*>(&partial[ks][c0]) =
            (f32x4){acc[0], acc[1], acc[2], acc[3]};
        *reinterpret_cast<f32x4*>(&partial[ks][c0 + 4]) =
            (f32x4){acc[4], acc[5], acc[6], acc[7]};
        __syncthreads();                                     // B1

        // reduce own column (= tid): 8 b32 reads, conflict-free
        float z = xw;
#pragma unroll
        for (int k2 = 0; k2 < 8; ++k2) z += partial[k2][tid];
        float h = fast_tanh(z);
        outn[(size_t)t * HH + tid] = h;
        ((__half*)hp[cur ^ 1])[tid] = __float2half(h);
        __syncthreads();                                     // B2
        cur ^= 1;
    }
}

// ---------------------------------------------------------------------------
extern "C" void kernel_launch(void* const* d_in, const int* in_sizes, int n_in,
                              void* d_out, int out_size, void* d_ws, size_t ws_size,
                              hipStream_t stream) {
    const float* x  = (const float*)d_in[0];   // (N, T, D)
    const float* h0 = (const float*)d_in[1];   // (N, H)
    const float* Wx = (const float*)d_in[2];   // (D, H)
    const float* Wh = (const float*)d_in[3];   // (H, H)
    const float* b  = (const float*)d_in[4];   // (H)
    float* out = (float*)d_out;                // (N, T, H)

    const long   M    = (long)NB * TT;         // 65536
    const size_t wt_b = (size_t)HH * DD * 2;   // 512 KB

    if (ws_size >= wt_b) {
        unsigned short* Wt = (unsigned short*)d_ws;
        conv_wt<<<HH, 64, 0, stream>>>(Wx, Wt);
        dim3 gg(M / GBM, HH / GBN);
        gemm_bf16f<<<gg, 256, 0, stream>>>(x, Wt, b, out);
    } else {
        dim3 g1(M / BM, HH / BN);
        gemm_xw<<<g1, 256, 0, stream>>>(x, Wx, b, out);
    }
    rnn_scan_wb<<<NB, 512, 0, stream>>>(Wh, h0, out);
}

// Round 16
// 1491.383 us; speedup vs baseline: 1.2484x; 1.1711x over previous
//
#include <hip/hip_runtime.h>
#include <hip/hip_fp16.h>
#include <cstddef>
#include <cstdint>

#define NB 64
#define TT 1024
#define DD 512
#define HH 512

typedef _Float16 h2_t __attribute__((ext_vector_type(2)));
typedef __attribute__((ext_vector_type(8))) short bf16x8;
typedef __attribute__((ext_vector_type(4))) float f32x4;
typedef __attribute__((ext_vector_type(8))) unsigned short ushort8;

__device__ __forceinline__ float dot2f(uint32_t a, uint32_t b, float c) {
#if __has_builtin(__builtin_amdgcn_fdot2)
    return __builtin_amdgcn_fdot2(__builtin_bit_cast(h2_t, a),
                                  __builtin_bit_cast(h2_t, b), c, false);
#else
    __half2 av = __builtin_bit_cast(__half2, a);
    __half2 bv = __builtin_bit_cast(__half2, b);
    float2 af = __half22float2(av), bf = __half22float2(bv);
    return fmaf(af.x, bf.x, fmaf(af.y, bf.y, c));
#endif
}

// fast tanh: |err| ~1e-7 (validated r5/r8)
__device__ __forceinline__ float fast_tanh(float z) {
    z = fmaxf(-15.f, fminf(15.f, z));
    float u = __builtin_amdgcn_exp2f(-2.885390082f * z);
    return (1.f - u) * __builtin_amdgcn_rcpf(1.f + u);
}

// fp32 -> bf16 bits, round-to-nearest-even
__device__ __forceinline__ unsigned short f2bf(float f) {
    uint32_t u = __builtin_bit_cast(uint32_t, f);
    u += 0x7FFFu + ((u >> 16) & 1u);
    return (unsigned short)(u >> 16);
}

// ---------------------------------------------------------------------------
// Prep: Wt[n][k] = bf16(Wx[k][n])  (tiny, ~5us)
// ---------------------------------------------------------------------------
__global__ void conv_wt(const float* __restrict__ W,
                        unsigned short* __restrict__ Wt) {
    int n = blockIdx.x;
    int kc = threadIdx.x;   // 0..63
    ushort8 o;
#pragma unroll
    for (int i = 0; i < 8; ++i)
        o[i] = f2bf(W[(size_t)(kc * 8 + i) * HH + n]);
    *reinterpret_cast<ushort8*>(&Wt[(size_t)n * DD + kc * 8]) = o;
}

// ---------------------------------------------------------------------------
// Kernel 1: fused MFMA bf16 GEMM (r12-validated; FETCH 70MB, ~85us w/ prep)
// ---------------------------------------------------------------------------
#define GBM 128
#define GBN 128
#define GBK 64
#define LDSW 72

__global__ __launch_bounds__(256, 4) void gemm_bf16f(
    const float* __restrict__ X,            // (M, K) fp32 row-major
    const unsigned short* __restrict__ Bt,  // (N, K) bf16 row-major (= Wx^T)
    const float* __restrict__ bias,
    float* __restrict__ C)                  // (M, H) fp32
{
    __shared__ unsigned short As[GBM * LDSW];
    __shared__ unsigned short Bs[GBN * LDSW];

    const int tid  = threadIdx.x;
    const int m0   = blockIdx.x * GBM;
    const int n0   = blockIdx.y * GBN;
    const int lane = tid & 63;
    const int wave = tid >> 6;
    const int wm   = wave >> 1;
    const int wn   = wave & 1;

    const int axr = tid >> 1;
    const int axc = (tid & 1) * 32;
    const int srow = tid >> 3;
    const int sch  = tid & 7;

    f32x4 acc[4][4] = {};

    const int arow = wm * 64 + (lane & 15);
    const int brow = wn * 64 + (lane & 15);
    const int koff = (lane >> 4) * 8;

    for (int kt = 0; kt < DD / GBK; ++kt) {
        const int k0 = kt * GBK;
        {
            const float* xp = &X[(size_t)(m0 + axr) * DD + k0 + axc];
#pragma unroll
            for (int i = 0; i < 4; ++i) {
                float4 a = *reinterpret_cast<const float4*>(&xp[i * 8]);
                float4 b = *reinterpret_cast<const float4*>(&xp[i * 8 + 4]);
                ushort8 o;
                o[0] = f2bf(a.x); o[1] = f2bf(a.y);
                o[2] = f2bf(a.z); o[3] = f2bf(a.w);
                o[4] = f2bf(b.x); o[5] = f2bf(b.y);
                o[6] = f2bf(b.z); o[7] = f2bf(b.w);
                *reinterpret_cast<ushort8*>(&As[axr * LDSW + axc + i * 8]) = o;
            }
        }
#pragma unroll
        for (int p = 0; p < 4; ++p) {
            const int row = srow + p * 32;
            *reinterpret_cast<ushort8*>(&Bs[row * LDSW + sch * 8]) =
                *reinterpret_cast<const ushort8*>(
                    &Bt[(size_t)(n0 + row) * DD + k0 + sch * 8]);
        }
        __syncthreads();

#pragma unroll
        for (int kk = 0; kk < GBK; kk += 32) {
            bf16x8 af[4], bf[4];
#pragma unroll
            for (int mt = 0; mt < 4; ++mt)
                af[mt] = *reinterpret_cast<const bf16x8*>(
                    &As[(arow + mt * 16) * LDSW + kk + koff]);
#pragma unroll
            for (int nt = 0; nt < 4; ++nt)
                bf[nt] = *reinterpret_cast<const bf16x8*>(
                    &Bs[(brow + nt * 16) * LDSW + kk + koff]);
#pragma unroll
            for (int mt = 0; mt < 4; ++mt)
#pragma unroll
                for (int nt = 0; nt < 4; ++nt)
                    acc[mt][nt] = __builtin_amdgcn_mfma_f32_16x16x32_bf16(
                        af[mt], bf[nt], acc[mt][nt], 0, 0, 0);
        }
        __syncthreads();
    }

#pragma unroll
    for (int nt = 0; nt < 4; ++nt) {
        const int col = n0 + wn * 64 + nt * 16 + (lane & 15);
        const float bv = bias[col];
#pragma unroll
        for (int mt = 0; mt < 4; ++mt) {
            const int rbase = m0 + wm * 64 + mt * 16 + (lane >> 4) * 4;
#pragma unroll
            for (int r = 0; r < 4; ++r)
                C[(size_t)(rbase + r) * HH + col] = acc[mt][nt][r] + bv;
        }
    }
}

// ---------------------------------------------------------------------------
// Kernel 1 (fallback): fp32 VALU GEMM
// ---------------------------------------------------------------------------
#define BM 128
#define BN 128
#define BK 8

__global__ __launch_bounds__(256, 2) void gemm_xw(
    const float* __restrict__ A,
    const float* __restrict__ B,
    const float* __restrict__ bias,
    float* __restrict__ C)
{
    __shared__ float As[BK][BM];
    __shared__ float Bs[BK][BN];

    const int tid  = threadIdx.x;
    const int tm   = tid >> 4;
    const int tn   = tid & 15;
    const int row0 = blockIdx.x * BM;
    const int col0 = blockIdx.y * BN;

    const int ar = tid >> 1;
    const int ac = (tid & 1) * 4;
    const int br = tid >> 5;
    const int bc = (tid & 31) * 4;

    float acc[8][8];
#pragma unroll
    for (int i = 0; i < 8; ++i)
#pragma unroll
        for (int j = 0; j < 8; ++j) acc[i][j] = 0.f;

    for (int k0 = 0; k0 < DD; k0 += BK) {
        float4 av = *reinterpret_cast<const float4*>(
            &A[(size_t)(row0 + ar) * DD + k0 + ac]);
        float4 bv = *reinterpret_cast<const float4*>(
            &B[(size_t)(k0 + br) * HH + col0 + bc]);

        As[ac + 0][ar] = av.x;
        As[ac + 1][ar] = av.y;
        As[ac + 2][ar] = av.z;
        As[ac + 3][ar] = av.w;
        *reinterpret_cast<float4*>(&Bs[br][bc]) = bv;
        __syncthreads();

#pragma unroll
        for (int kk = 0; kk < BK; ++kk) {
            float a[8], b[8];
            *reinterpret_cast<float4*>(&a[0]) =
                *reinterpret_cast<const float4*>(&As[kk][tm * 8]);
            *reinterpret_cast<float4*>(&a[4]) =
                *reinterpret_cast<const float4*>(&As[kk][tm * 8 + 4]);
            *reinterpret_cast<float4*>(&b[0]) =
                *reinterpret_cast<const float4*>(&Bs[kk][tn * 8]);
            *reinterpret_cast<float4*>(&b[4]) =
                *reinterpret_cast<const float4*>(&Bs[kk][tn * 8 + 4]);
#pragma unroll
            for (int i = 0; i < 8; ++i)
#pragma unroll
                for (int j = 0; j < 8; ++j)
                    acc[i][j] = fmaf(a[i], b[j], acc[i][j]);
        }
        __syncthreads();
    }

#pragma unroll
    for (int i = 0; i < 8; ++i) {
        const int row = row0 + tm * 8 + i;
#pragma unroll
        for (int j = 0; j < 8; j += 4) {
            const int col = col0 + tn * 8 + j;
            float4 o;
            o.x = acc[i][j + 0] + bias[col + 0];
            o.y = acc[i][j + 1] + bias[col + 1];
            o.z = acc[i][j + 2] + bias[col + 2];
            o.w = acc[i][j + 3] + bias[col + 3];
            *reinterpret_cast<float4*>(&C[(size_t)row * HH + col]) = o;
        }
    }
}

// ---------------------------------------------------------------------------
// Kernel 2: grouped scan — consolidated sync protocol.
//  - r11/r4 structure: 256 blocks x 1024 threads, 4 blocks/batch, weight
//    slice register-resident packed fp16, 16-wave dot, 2 barriers/step.
//  - Publish: pair-packed packet {tag T : 32, half2(h0,h1) : 32} via
//    global_atomic_swap_x2 (memory-side serialization point, placement-
//    independent -> no rendezvous, no dual region). 64 swaps/block-step.
//  - Poll: PURE relaxed agent-scope loads (read-only, no atomic-unit
//    write pressure — r12/r13 showed RMW polling adds contention).
//    192 pollers/block, one packet each, ~600cy natural period.
//  - Replay-safe: stale tags mismatch, or (T=1023/1024 parity tails)
//    carry bit-identical deterministic values; 0xAA never matches a tag.
//  - Deadlock-free: all 256 blocks co-resident (bounds(1024,4), 10KB LDS).
// ---------------------------------------------------------------------------
__global__ __launch_bounds__(1024, 4) void rnn_scan_fin(
    const float* __restrict__ Wh,    // (H, H) fp32 row-major
    const float* __restrict__ h0,    // (N, H)
    float* __restrict__ out,         // (N, T, H): in = xw, out = h
    uint64_t* __restrict__ exch)     // [NB][2][256] pair packets
{
    __shared__ __align__(16) uint32_t hp[2][HH / 2];
    __shared__ float partial[16][128];

    const int blk = blockIdx.x;
    const int n   = blk & 63;          // batch
    const int r   = blk >> 6;          // role 0..3
    const int jb  = r << 7;            // column base (0,128,256,384)
    const int pb  = r << 6;            // packet base (0,64,128,192)

    const int tid = threadIdx.x;
    const int w = tid >> 6;            // wave 0..15 -> k slice [w*32,+32)
    const int l = tid & 63;            // lane -> columns jb+l, jb+64+l

    // ---- one-time: weight slice -> registers as packed fp16 ----
    uint32_t w0[16], w1[16];
    {
        const float* wc = Wh + (size_t)(w * 32) * HH + jb + l;
#pragma unroll
        for (int p = 0; p < 16; ++p) {
            float e0 = wc[(size_t)(2 * p) * HH];
            float e1 = wc[(size_t)(2 * p + 1) * HH];
            w0[p] = __builtin_bit_cast(uint32_t, __floats2half2_rn(e0, e1));
            float f0 = wc[(size_t)(2 * p) * HH + 64];
            float f1 = wc[(size_t)(2 * p + 1) * HH + 64];
            w1[p] = __builtin_bit_cast(uint32_t, __floats2half2_rn(f0, f1));
        }
    }

    if (tid < HH)
        ((__half*)hp[0])[tid] = __float2half(h0[(size_t)n * HH + tid]);
    __syncthreads();

    float* outn = out + (size_t)n * TT * HH;
    uint64_t* ex = exch + (size_t)n * 2 * 256;

    // poller packet index (tid in [64,256)): the 192 remote packets
    const int ppi = (pb + 64 + (tid - 64)) & 255;

    int cur = 0;
    for (int t = 0; t < TT; ++t) {
        const uint32_t T = (uint32_t)(t + 1);
        const int slot = (int)(T & 1u);

        // prefetch xw for own column pair (consumed after B1)
        float2 xw2 = {0.f, 0.f};
        if (tid < 64)
            xw2 = *reinterpret_cast<const float2*>(
                &outn[(size_t)t * HH + jb + 2 * tid]);

        // partial dot over k slice [w*32,+32) for cols jb+l, jb+64+l
        const uint32_t* hpw = &hp[cur][w * 16];
        float a0 = 0.f, a1 = 0.f, b0 = 0.f, b1 = 0.f;
#pragma unroll
        for (int q = 0; q < 4; ++q) {
            uint4 hv = ((const uint4*)hpw)[q];
            a0 = dot2f(hv.x, w0[4 * q + 0], a0);
            b0 = dot2f(hv.x, w1[4 * q + 0], b0);
            a1 = dot2f(hv.y, w0[4 * q + 1], a1);
            b1 = dot2f(hv.y, w1[4 * q + 1], b1);
            a0 = dot2f(hv.z, w0[4 * q + 2], a0);
            b0 = dot2f(hv.z, w1[4 * q + 2], b0);
            a1 = dot2f(hv.w, w0[4 * q + 3], a1);
            b1 = dot2f(hv.w, w1[4 * q + 3], b1);
        }
        partial[w][l] = a0 + a1;
        partial[w][64 + l] = b0 + b1;
        __syncthreads();                                      // B1

        uint32_t* hpn32 = hp[cur ^ 1];
        if (tid < 64) {
            // producer: reduce TWO cols, tanh, pack, ONE swap publish
            float s0 = 0.f, s1 = 0.f;
#pragma unroll
            for (int ww = 0; ww < 16; ++ww) {
                float2 pv = *reinterpret_cast<const float2*>(
                    &partial[ww][2 * tid]);
                s0 += pv.x; s1 += pv.y;
            }
            float hh0 = fast_tanh(s0 + xw2.x);
            float hh1 = fast_tanh(s1 + xw2.y);
            uint32_t ph = __builtin_bit_cast(uint32_t,
                                             __floats2half2_rn(hh0, hh1));
            uint64_t pk = ((uint64_t)T << 32) | ph;
            const int idx = slot * 256 + pb + tid;
            // publish FIRST (critical path), side-writes after
            asm volatile("global_atomic_swap_x2 %0, %1, off"
                         :: "v"((uint64_t)&ex[idx]), "v"(pk) : "memory");
            float2 ov; ov.x = hh0; ov.y = hh1;
            *reinterpret_cast<float2*>(
                &outn[(size_t)t * HH + jb + 2 * tid]) = ov;
            hpn32[pb + tid] = ph;
        } else if (tid < 256) {
            // poller: pure-load spin on one remote packet (no writes)
            const int idx = slot * 256 + ppi;
            uint64_t v = __hip_atomic_load(&ex[idx], __ATOMIC_RELAXED,
                                           __HIP_MEMORY_SCOPE_AGENT);
            while ((uint32_t)(v >> 32) != T) {
                v = __hip_atomic_load(&ex[idx], __ATOMIC_RELAXED,
                                      __HIP_MEMORY_SCOPE_AGENT);
            }
            hpn32[ppi] = (uint32_t)v;
        }
        __syncthreads();                                      // B2
        cur ^= 1;
    }
}

// ---------------------------------------------------------------------------
// Fallback scan (no workspace needed)
// ---------------------------------------------------------------------------
__global__ __launch_bounds__(512, 2) void rnn_scan_f32(
    const float* __restrict__ Wh,
    const float* __restrict__ h0,
    float* __restrict__ out)
{
    __shared__ float hbuf[2][HH];
    const int n = blockIdx.x;
    const int j = threadIdx.x;

    hbuf[0][j] = h0[(size_t)n * HH + j];
    __syncthreads();

    float* outn = out + (size_t)n * TT * HH;
    const float* __restrict__ wp = Wh + j;

    int cur = 0;
    for (int t = 0; t < TT; ++t) {
        float acc = outn[(size_t)t * HH + j];
        const float* hc = hbuf[cur];
#pragma unroll 4
        for (int k = 0; k < HH; k += 4) {
            float4 hv = *reinterpret_cast<const float4*>(&hc[k]);
            acc = fmaf(hv.x, wp[(size_t)(k + 0) * HH], acc);
            acc = fmaf(hv.y, wp[(size_t)(k + 1) * HH], acc);
            acc = fmaf(hv.z, wp[(size_t)(k + 2) * HH], acc);
            acc = fmaf(hv.w, wp[(size_t)(k + 3) * HH], acc);
        }
        float hn = tanhf(acc);
        outn[(size_t)t * HH + j] = hn;
        hbuf[cur ^ 1][j] = hn;
        cur ^= 1;
        __syncthreads();
    }
}

// ---------------------------------------------------------------------------
extern "C" void kernel_launch(void* const* d_in, const int* in_sizes, int n_in,
                              void* d_out, int out_size, void* d_ws, size_t ws_size,
                              hipStream_t stream) {
    const float* x  = (const float*)d_in[0];   // (N, T, D)
    const float* h0 = (const float*)d_in[1];   // (N, H)
    const float* Wx = (const float*)d_in[2];   // (D, H)
    const float* Wh = (const float*)d_in[3];   // (H, H)
    const float* b  = (const float*)d_in[4];   // (H)
    float* out = (float*)d_out;                // (N, T, H)

    const long   M      = (long)NB * TT;                 // 65536
    const size_t pkt_b  = (size_t)NB * 2 * 256 * 8;      // 256 KB
    const size_t wt_b   = (size_t)HH * DD * 2;           // 512 KB
    const size_t need_all = pkt_b + wt_b;
    const size_t need_mid = pkt_b;

    if (ws_size >= need_all) {
        uint64_t*       exch = (uint64_t*)d_ws;
        unsigned short* Wt   = (unsigned short*)((char*)d_ws + pkt_b);

        conv_wt<<<HH, 64, 0, stream>>>(Wx, Wt);
        dim3 gg(M / GBM, HH / GBN);
        gemm_bf16f<<<gg, 256, 0, stream>>>(x, Wt, b, out);
        rnn_scan_fin<<<256, 1024, 0, stream>>>(Wh, h0, out, exch);
    } else if (ws_size >= need_mid) {
        uint64_t* exch = (uint64_t*)d_ws;
        dim3 g1(M / BM, HH / BN);
        gemm_xw<<<g1, 256, 0, stream>>>(x, Wx, b, out);
        rnn_scan_fin<<<256, 1024, 0, stream>>>(Wh, h0, out, exch);
    } else {
        dim3 g1(M / BM, HH / BN);
        gemm_xw<<<g1, 256, 0, stream>>>(x, Wx, b, out);
        rnn_scan_f32<<<NB, 512, 0, stream>>>(Wh, h0, out);
    }
}

// Round 17
// 1430.715 us; speedup vs baseline: 1.3014x; 1.0424x over previous
//
#include <hip/hip_runtime.h>
#include <hip/hip_fp16.h>
#include <cstddef>
#include <cstdint>

#define NB 64
#define TT 1024
#define DD 512
#define HH 512

typedef _Float16 h2_t __attribute__((ext_vector_type(2)));
typedef __attribute__((ext_vector_type(8))) short bf16x8;
typedef __attribute__((ext_vector_type(4))) float f32x4;
typedef __attribute__((ext_vector_type(8))) unsigned short ushort8;

__device__ __forceinline__ float dot2f(uint32_t a, uint32_t b, float c) {
#if __has_builtin(__builtin_amdgcn_fdot2)
    return __builtin_amdgcn_fdot2(__builtin_bit_cast(h2_t, a),
                                  __builtin_bit_cast(h2_t, b), c, false);
#else
    __half2 av = __builtin_bit_cast(__half2, a);
    __half2 bv = __builtin_bit_cast(__half2, b);
    float2 af = __half22float2(av), bf = __half22float2(bv);
    return fmaf(af.x, bf.x, fmaf(af.y, bf.y, c));
#endif
}

// fast tanh: |err| ~1e-7 (validated r5/r8)
__device__ __forceinline__ float fast_tanh(float z) {
    z = fmaxf(-15.f, fminf(15.f, z));
    float u = __builtin_amdgcn_exp2f(-2.885390082f * z);
    return (1.f - u) * __builtin_amdgcn_rcpf(1.f + u);
}

// fp32 -> bf16 bits, round-to-nearest-even
__device__ __forceinline__ unsigned short f2bf(float f) {
    uint32_t u = __builtin_bit_cast(uint32_t, f);
    u += 0x7FFFu + ((u >> 16) & 1u);
    return (unsigned short)(u >> 16);
}

// ---------------------------------------------------------------------------
// Prep: Wt[n][k] = bf16(Wx[k][n])  (tiny, ~5us)
// ---------------------------------------------------------------------------
__global__ void conv_wt(const float* __restrict__ W,
                        unsigned short* __restrict__ Wt) {
    int n = blockIdx.x;
    int kc = threadIdx.x;   // 0..63
    ushort8 o;
#pragma unroll
    for (int i = 0; i < 8; ++i)
        o[i] = f2bf(W[(size_t)(kc * 8 + i) * HH + n]);
    *reinterpret_cast<ushort8*>(&Wt[(size_t)n * DD + kc * 8]) = o;
}

// ---------------------------------------------------------------------------
// Kernel 1: fused MFMA bf16 GEMM (r12-validated; FETCH 70MB, ~85us w/ prep)
// ---------------------------------------------------------------------------
#define GBM 128
#define GBN 128
#define GBK 64
#define LDSW 72

__global__ __launch_bounds__(256, 4) void gemm_bf16f(
    const float* __restrict__ X,            // (M, K) fp32 row-major
    const unsigned short* __restrict__ Bt,  // (N, K) bf16 row-major (= Wx^T)
    const float* __restrict__ bias,
    float* __restrict__ C)                  // (M, H) fp32
{
    __shared__ unsigned short As[GBM * LDSW];
    __shared__ unsigned short Bs[GBN * LDSW];

    const int tid  = threadIdx.x;
    const int m0   = blockIdx.x * GBM;
    const int n0   = blockIdx.y * GBN;
    const int lane = tid & 63;
    const int wave = tid >> 6;
    const int wm   = wave >> 1;
    const int wn   = wave & 1;

    const int axr = tid >> 1;
    const int axc = (tid & 1) * 32;
    const int srow = tid >> 3;
    const int sch  = tid & 7;

    f32x4 acc[4][4] = {};

    const int arow = wm * 64 + (lane & 15);
    const int brow = wn * 64 + (lane & 15);
    const int koff = (lane >> 4) * 8;

    for (int kt = 0; kt < DD / GBK; ++kt) {
        const int k0 = kt * GBK;
        {
            const float* xp = &X[(size_t)(m0 + axr) * DD + k0 + axc];
#pragma unroll
            for (int i = 0; i < 4; ++i) {
                float4 a = *reinterpret_cast<const float4*>(&xp[i * 8]);
                float4 b = *reinterpret_cast<const float4*>(&xp[i * 8 + 4]);
                ushort8 o;
                o[0] = f2bf(a.x); o[1] = f2bf(a.y);
                o[2] = f2bf(a.z); o[3] = f2bf(a.w);
                o[4] = f2bf(b.x); o[5] = f2bf(b.y);
                o[6] = f2bf(b.z); o[7] = f2bf(b.w);
                *reinterpret_cast<ushort8*>(&As[axr * LDSW + axc + i * 8]) = o;
            }
        }
#pragma unroll
        for (int p = 0; p < 4; ++p) {
            const int row = srow + p * 32;
            *reinterpret_cast<ushort8*>(&Bs[row * LDSW + sch * 8]) =
                *reinterpret_cast<const ushort8*>(
                    &Bt[(size_t)(n0 + row) * DD + k0 + sch * 8]);
        }
        __syncthreads();

#pragma unroll
        for (int kk = 0; kk < GBK; kk += 32) {
            bf16x8 af[4], bf[4];
#pragma unroll
            for (int mt = 0; mt < 4; ++mt)
                af[mt] = *reinterpret_cast<const bf16x8*>(
                    &As[(arow + mt * 16) * LDSW + kk + koff]);
#pragma unroll
            for (int nt = 0; nt < 4; ++nt)
                bf[nt] = *reinterpret_cast<const bf16x8*>(
                    &Bs[(brow + nt * 16) * LDSW + kk + koff]);
#pragma unroll
            for (int mt = 0; mt < 4; ++mt)
#pragma unroll
                for (int nt = 0; nt < 4; ++nt)
                    acc[mt][nt] = __builtin_amdgcn_mfma_f32_16x16x32_bf16(
                        af[mt], bf[nt], acc[mt][nt], 0, 0, 0);
        }
        __syncthreads();
    }

#pragma unroll
    for (int nt = 0; nt < 4; ++nt) {
        const int col = n0 + wn * 64 + nt * 16 + (lane & 15);
        const float bv = bias[col];
#pragma unroll
        for (int mt = 0; mt < 4; ++mt) {
            const int rbase = m0 + wm * 64 + mt * 16 + (lane >> 4) * 4;
#pragma unroll
            for (int r = 0; r < 4; ++r)
                C[(size_t)(rbase + r) * HH + col] = acc[mt][nt][r] + bv;
        }
    }
}

// ---------------------------------------------------------------------------
// Kernel 1 (fallback): fp32 VALU GEMM
// ---------------------------------------------------------------------------
#define BM 128
#define BN 128
#define BK 8

__global__ __launch_bounds__(256, 2) void gemm_xw(
    const float* __restrict__ A,
    const float* __restrict__ B,
    const float* __restrict__ bias,
    float* __restrict__ C)
{
    __shared__ float As[BK][BM];
    __shared__ float Bs[BK][BN];

    const int tid  = threadIdx.x;
    const int tm   = tid >> 4;
    const int tn   = tid & 15;
    const int row0 = blockIdx.x * BM;
    const int col0 = blockIdx.y * BN;

    const int ar = tid >> 1;
    const int ac = (tid & 1) * 4;
    const int br = tid >> 5;
    const int bc = (tid & 31) * 4;

    float acc[8][8];
#pragma unroll
    for (int i = 0; i < 8; ++i)
#pragma unroll
        for (int j = 0; j < 8; ++j) acc[i][j] = 0.f;

    for (int k0 = 0; k0 < DD; k0 += BK) {
        float4 av = *reinterpret_cast<const float4*>(
            &A[(size_t)(row0 + ar) * DD + k0 + ac]);
        float4 bv = *reinterpret_cast<const float4*>(
            &B[(size_t)(k0 + br) * HH + col0 + bc]);

        As[ac + 0][ar] = av.x;
        As[ac + 1][ar] = av.y;
        As[ac + 2][ar] = av.z;
        As[ac + 3][ar] = av.w;
        *reinterpret_cast<float4*>(&Bs[br][bc]) = bv;
        __syncthreads();

#pragma unroll
        for (int kk = 0; kk < BK; ++kk) {
            float a[8], b[8];
            *reinterpret_cast<float4*>(&a[0]) =
                *reinterpret_cast<const float4*>(&As[kk][tm * 8]);
            *reinterpret_cast<float4*>(&a[4]) =
                *reinterpret_cast<const float4*>(&As[kk][tm * 8 + 4]);
            *reinterpret_cast<float4*>(&b[0]) =
                *reinterpret_cast<const float4*>(&Bs[kk][tn * 8]);
            *reinterpret_cast<float4*>(&b[4]) =
                *reinterpret_cast<const float4*>(&Bs[kk][tn * 8 + 4]);
#pragma unroll
            for (int i = 0; i < 8; ++i)
#pragma unroll
                for (int j = 0; j < 8; ++j)
                    acc[i][j] = fmaf(a[i], b[j], acc[i][j]);
        }
        __syncthreads();
    }

#pragma unroll
    for (int i = 0; i < 8; ++i) {
        const int row = row0 + tm * 8 + i;
#pragma unroll
        for (int j = 0; j < 8; j += 4) {
            const int col = col0 + tn * 8 + j;
            float4 o;
            o.x = acc[i][j + 0] + bias[col + 0];
            o.y = acc[i][j + 1] + bias[col + 1];
            o.z = acc[i][j + 2] + bias[col + 2];
            o.w = acc[i][j + 3] + bias[col + 3];
            *reinterpret_cast<float4*>(&C[(size_t)row * HH + col]) = o;
        }
    }
}

// ---------------------------------------------------------------------------
// Kernel 2: grouped scan — r11 poll cadence x r13 pair-packing.
//  - r4/r11 skeleton: 256 blocks x 1024 threads, 4 blocks/batch, weight
//    slice register-resident packed fp16, 16-wave dot, 2 barriers/step.
//  - Packet: {tag T : 32, half2(h[2p],h[2p+1]) : 32}. 64 publishes +
//    192 pollers per block-step (HALF of r11's counts).
//  - Publish: global_atomic_swap_x2 to mirror (memory-side serialization
//    point, placement-independent -> static decode, no rendezvous);
//    then side-writes; then relaxed agent truth store (poll channel 2).
//  - Poll (r11's proven cadence, no sleep): alternate returning
//    atomic_add_x2(0) on mirror (fresh, serialization point) with a
//    relaxed agent truth load (natural spacing, second detect channel).
//  - Replay-safe: stale tags mismatch or carry bit-identical
//    deterministic values; 0xAA poison never matches a tag.
//  - Deadlock-free: all 256 blocks co-resident (bounds(1024,4), 10KB LDS).
// ---------------------------------------------------------------------------
__global__ __launch_bounds__(1024, 4) void rnn_scan_v17(
    const float* __restrict__ Wh,     // (H, H) fp32 row-major
    const float* __restrict__ h0,     // (N, H)
    float* __restrict__ out,          // (N, T, H): in = xw, out = h
    uint64_t* __restrict__ truth,     // [NB][2][256] agent packets
    uint64_t* __restrict__ mirror)    // [NB][2][256] RMW packets
{
    __shared__ __align__(16) uint32_t hp[2][HH / 2];
    __shared__ float partial[16][128];

    const int blk = blockIdx.x;
    const int n   = blk & 63;          // batch
    const int r   = blk >> 6;          // role 0..3
    const int jb  = r << 7;            // column base (0,128,256,384)
    const int pb  = r << 6;            // packet base (0,64,128,192)

    const int tid = threadIdx.x;
    const int w = tid >> 6;            // wave 0..15 -> k slice [w*32,+32)
    const int l = tid & 63;            // lane -> columns jb+l, jb+64+l

    // ---- one-time: weight slice -> registers as packed fp16 ----
    uint32_t w0[16], w1[16];
    {
        const float* wc = Wh + (size_t)(w * 32) * HH + jb + l;
#pragma unroll
        for (int p = 0; p < 16; ++p) {
            float e0 = wc[(size_t)(2 * p) * HH];
            float e1 = wc[(size_t)(2 * p + 1) * HH];
            w0[p] = __builtin_bit_cast(uint32_t, __floats2half2_rn(e0, e1));
            float f0 = wc[(size_t)(2 * p) * HH + 64];
            float f1 = wc[(size_t)(2 * p + 1) * HH + 64];
            w1[p] = __builtin_bit_cast(uint32_t, __floats2half2_rn(f0, f1));
        }
    }

    if (tid < HH)
        ((__half*)hp[0])[tid] = __float2half(h0[(size_t)n * HH + tid]);
    __syncthreads();

    float* outn = out + (size_t)n * TT * HH;
    uint64_t* tru = truth  + (size_t)n * 2 * 256;
    uint64_t* mir = mirror + (size_t)n * 2 * 256;

    // poller packet index (tid in [64,256)): the 192 remote packets
    const int ppi = (pb + 64 + (tid - 64)) & 255;

    int cur = 0;
    for (int t = 0; t < TT; ++t) {
        const uint32_t T = (uint32_t)(t + 1);
        const int slot = (int)(T & 1u);

        // prefetch xw for own column pair (consumed after B1)
        float2 xw2 = {0.f, 0.f};
        if (tid < 64)
            xw2 = *reinterpret_cast<const float2*>(
                &outn[(size_t)t * HH + jb + 2 * tid]);

        // partial dot over k slice [w*32,+32) for cols jb+l, jb+64+l
        const uint32_t* hpw = &hp[cur][w * 16];
        float a0 = 0.f, a1 = 0.f, b0 = 0.f, b1 = 0.f;
#pragma unroll
        for (int q = 0; q < 4; ++q) {
            uint4 hv = ((const uint4*)hpw)[q];
            a0 = dot2f(hv.x, w0[4 * q + 0], a0);
            b0 = dot2f(hv.x, w1[4 * q + 0], b0);
            a1 = dot2f(hv.y, w0[4 * q + 1], a1);
            b1 = dot2f(hv.y, w1[4 * q + 1], b1);
            a0 = dot2f(hv.z, w0[4 * q + 2], a0);
            b0 = dot2f(hv.z, w1[4 * q + 2], b0);
            a1 = dot2f(hv.w, w0[4 * q + 3], a1);
            b1 = dot2f(hv.w, w1[4 * q + 3], b1);
        }
        partial[w][l] = a0 + a1;
        partial[w][64 + l] = b0 + b1;
        __syncthreads();                                      // B1

        uint32_t* hpn32 = hp[cur ^ 1];
        if (tid < 64) {
            // producer: reduce TWO cols, tanh, pack, swap publish FIRST
            float s0 = 0.f, s1 = 0.f;
#pragma unroll
            for (int ww = 0; ww < 16; ++ww) {
                float2 pv = *reinterpret_cast<const float2*>(
                    &partial[ww][2 * tid]);
                s0 += pv.x; s1 += pv.y;
            }
            float hh0 = fast_tanh(s0 + xw2.x);
            float hh1 = fast_tanh(s1 + xw2.y);
            uint32_t ph = __builtin_bit_cast(uint32_t,
                                             __floats2half2_rn(hh0, hh1));
            uint64_t pk = ((uint64_t)T << 32) | ph;
            const int idx = slot * 256 + pb + tid;
            asm volatile("global_atomic_swap_x2 %0, %1, off"
                         :: "v"((uint64_t)&mir[idx]), "v"(pk) : "memory");
            float2 ov; ov.x = hh0; ov.y = hh1;
            *reinterpret_cast<float2*>(
                &outn[(size_t)t * HH + jb + 2 * tid]) = ov;
            hpn32[pb + tid] = ph;
            __hip_atomic_store(&tru[idx], pk, __ATOMIC_RELAXED,
                               __HIP_MEMORY_SCOPE_AGENT);     // channel 2
        } else if (tid < 256) {
            // poller: r11 cadence — RMW detect alternated with truth load
            const int idx = slot * 256 + ppi;
            const uint64_t maddr = (uint64_t)&mir[idx];
            const uint64_t zero = 0;
            uint64_t v;
            while (true) {
                asm volatile(
                    "global_atomic_add_x2 %0, %1, %2, off sc0\n\t"
                    "s_waitcnt vmcnt(0)"
                    : "=v"(v) : "v"(maddr), "v"(zero) : "memory");
                if ((uint32_t)(v >> 32) == T) break;
                v = __hip_atomic_load(&tru[idx], __ATOMIC_RELAXED,
                                      __HIP_MEMORY_SCOPE_AGENT);
                if ((uint32_t)(v >> 32) == T) break;
            }
            hpn32[ppi] = (uint32_t)v;
        }
        __syncthreads();                                      // B2
        cur ^= 1;
    }
}

// ---------------------------------------------------------------------------
// Fallback scan (no workspace needed)
// ---------------------------------------------------------------------------
__global__ __launch_bounds__(512, 2) void rnn_scan_f32(
    const float* __restrict__ Wh,
    const float* __restrict__ h0,
    float* __restrict__ out)
{
    __shared__ float hbuf[2][HH];
    const int n = blockIdx.x;
    const int j = threadIdx.x;

    hbuf[0][j] = h0[(size_t)n * HH + j];
    __syncthreads();

    float* outn = out + (size_t)n * TT * HH;
    const float* __restrict__ wp = Wh + j;

    int cur = 0;
    for (int t = 0; t < TT; ++t) {
        float acc = outn[(size_t)t * HH + j];
        const float* hc = hbuf[cur];
#pragma unroll 4
        for (int k = 0; k < HH; k += 4) {
            float4 hv = *reinterpret_cast<const float4*>(&hc[k]);
            acc = fmaf(hv.x, wp[(size_t)(k + 0) * HH], acc);
            acc = fmaf(hv.y, wp[(size_t)(k + 1) * HH], acc);
            acc = fmaf(hv.z, wp[(size_t)(k + 2) * HH], acc);
            acc = fmaf(hv.w, wp[(size_t)(k + 3) * HH], acc);
        }
        float hn = tanhf(acc);
        outn[(size_t)t * HH + j] = hn;
        hbuf[cur ^ 1][j] = hn;
        cur ^= 1;
        __syncthreads();
    }
}

// ---------------------------------------------------------------------------
extern "C" void kernel_launch(void* const* d_in, const int* in_sizes, int n_in,
                              void* d_out, int out_size, void* d_ws, size_t ws_size,
                              hipStream_t stream) {
    const float* x  = (const float*)d_in[0];   // (N, T, D)
    const float* h0 = (const float*)d_in[1];   // (N, H)
    const float* Wx = (const float*)d_in[2];   // (D, H)
    const float* Wh = (const float*)d_in[3];   // (H, H)
    const float* b  = (const float*)d_in[4];   // (H)
    float* out = (float*)d_out;                // (N, T, H)

    const long   M      = (long)NB * TT;                 // 65536
    const size_t pkt_b  = (size_t)NB * 2 * 256 * 8;      // 256 KB per region
    const size_t wt_b   = (size_t)HH * DD * 2;           // 512 KB
    const size_t need_all = 2 * pkt_b + wt_b;
    const size_t need_mid = 2 * pkt_b;

    if (ws_size >= need_all) {
        uint64_t*       truth  = (uint64_t*)d_ws;
        uint64_t*       mirror = (uint64_t*)((char*)d_ws + pkt_b);
        unsigned short* Wt     = (unsigned short*)((char*)d_ws + 2 * pkt_b);

        conv_wt<<<HH, 64, 0, stream>>>(Wx, Wt);
        dim3 gg(M / GBM, HH / GBN);
        gemm_bf16f<<<gg, 256, 0, stream>>>(x, Wt, b, out);
        rnn_scan_v17<<<256, 1024, 0, stream>>>(Wh, h0, out, truth, mirror);
    } else if (ws_size >= need_mid) {
        uint64_t* truth  = (uint64_t*)d_ws;
        uint64_t* mirror = (uint64_t*)((char*)d_ws + pkt_b);
        dim3 g1(M / BM, HH / BN);
        gemm_xw<<<g1, 256, 0, stream>>>(x, Wx, b, out);
        rnn_scan_v17<<<256, 1024, 0, stream>>>(Wh, h0, out, truth, mirror);
    } else {
        dim3 g1(M / BM, HH / BN);
        gemm_xw<<<g1, 256, 0, stream>>>(x, Wx, b, out);
        rnn_scan_f32<<<NB, 512, 0, stream>>>(Wh, h0, out);
    }
}

// Round 18
// 1369.689 us; speedup vs baseline: 1.3593x; 1.0446x over previous
//
#include <hip/hip_runtime.h>
#include <hip/hip_fp16.h>
#include <cstddef>
#include <cstdint>

#define NB 64
#define TT 1024
#define DD 512
#define HH 512

typedef _Float16 h2_t __attribute__((ext_vector_type(2)));
typedef __attribute__((ext_vector_type(8))) short bf16x8;
typedef __attribute__((ext_vector_type(4))) float f32x4;
typedef __attribute__((ext_vector_type(8))) unsigned short ushort8;

__device__ __forceinline__ float dot2f(uint32_t a, uint32_t b, float c) {
#if __has_builtin(__builtin_amdgcn_fdot2)
    return __builtin_amdgcn_fdot2(__builtin_bit_cast(h2_t, a),
                                  __builtin_bit_cast(h2_t, b), c, false);
#else
    __half2 av = __builtin_bit_cast(__half2, a);
    __half2 bv = __builtin_bit_cast(__half2, b);
    float2 af = __half22float2(av), bf = __half22float2(bv);
    return fmaf(af.x, bf.x, fmaf(af.y, bf.y, c));
#endif
}

// fast tanh: |err| ~1e-7 (validated r5/r8: absmax unchanged)
__device__ __forceinline__ float fast_tanh(float z) {
    z = fmaxf(-15.f, fminf(15.f, z));
    float u = __builtin_amdgcn_exp2f(-2.885390082f * z);
    return (1.f - u) * __builtin_amdgcn_rcpf(1.f + u);
}

// fp32 -> bf16 bits, round-to-nearest-even
__device__ __forceinline__ unsigned short f2bf(float f) {
    uint32_t u = __builtin_bit_cast(uint32_t, f);
    u += 0x7FFFu + ((u >> 16) & 1u);
    return (unsigned short)(u >> 16);
}

// ---------------------------------------------------------------------------
// Prep A: x (fp32) -> xb (bf16)
// ---------------------------------------------------------------------------
__global__ void conv_x(const float* __restrict__ x,
                       unsigned short* __restrict__ xb, long total) {
    long i0 = (long)(blockIdx.x * blockDim.x + threadIdx.x) * 8;
    long stride = (long)gridDim.x * blockDim.x * 8;
    for (long i = i0; i < total; i += stride) {
        float4 a = *reinterpret_cast<const float4*>(&x[i]);
        float4 b = *reinterpret_cast<const float4*>(&x[i + 4]);
        ushort8 o;
        o[0] = f2bf(a.x); o[1] = f2bf(a.y); o[2] = f2bf(a.z); o[3] = f2bf(a.w);
        o[4] = f2bf(b.x); o[5] = f2bf(b.y); o[6] = f2bf(b.z); o[7] = f2bf(b.w);
        *reinterpret_cast<ushort8*>(&xb[i]) = o;
    }
}

// ---------------------------------------------------------------------------
// Prep B: Wt[n][k] = bf16(Wx[k][n])
// ---------------------------------------------------------------------------
__global__ void conv_wt(const float* __restrict__ W,
                        unsigned short* __restrict__ Wt) {
    int n = blockIdx.x;
    int kc = threadIdx.x;   // 0..63
    ushort8 o;
#pragma unroll
    for (int i = 0; i < 8; ++i)
        o[i] = f2bf(W[(size_t)(kc * 8 + i) * HH + n]);
    *reinterpret_cast<ushort8*>(&Wt[(size_t)n * DD + kc * 8]) = o;
}

// ---------------------------------------------------------------------------
// Kernel 1: MFMA bf16 GEMM (validated round 8: ~70us incl. preps)
// ---------------------------------------------------------------------------
#define GBM 128
#define GBN 128
#define GBK 64
#define LDSW 72

__global__ __launch_bounds__(256, 4) void gemm_bf16(
    const unsigned short* __restrict__ A,
    const unsigned short* __restrict__ Bt,
    const float* __restrict__ bias,
    float* __restrict__ C)
{
    __shared__ unsigned short As[GBM * LDSW];
    __shared__ unsigned short Bs[GBN * LDSW];

    const int tid  = threadIdx.x;
    const int m0   = blockIdx.x * GBM;
    const int n0   = blockIdx.y * GBN;
    const int lane = tid & 63;
    const int wave = tid >> 6;
    const int wm   = wave >> 1;
    const int wn   = wave & 1;

    const int srow = tid >> 3;
    const int sch  = tid & 7;

    f32x4 acc[4][4] = {};

    const int arow = wm * 64 + (lane & 15);
    const int brow = wn * 64 + (lane & 15);
    const int koff = (lane >> 4) * 8;

    for (int kt = 0; kt < DD / GBK; ++kt) {
        const int k0 = kt * GBK;
#pragma unroll
        for (int p = 0; p < 4; ++p) {
            const int row = srow + p * 32;
            *reinterpret_cast<ushort8*>(&As[row * LDSW + sch * 8]) =
                *reinterpret_cast<const ushort8*>(
                    &A[(size_t)(m0 + row) * DD + k0 + sch * 8]);
            *reinterpret_cast<ushort8*>(&Bs[row * LDSW + sch * 8]) =
                *reinterpret_cast<const ushort8*>(
                    &Bt[(size_t)(n0 + row) * DD + k0 + sch * 8]);
        }
        __syncthreads();

#pragma unroll
        for (int kk = 0; kk < GBK; kk += 32) {
            bf16x8 af[4], bf[4];
#pragma unroll
            for (int mt = 0; mt < 4; ++mt)
                af[mt] = *reinterpret_cast<const bf16x8*>(
                    &As[(arow + mt * 16) * LDSW + kk + koff]);
#pragma unroll
            for (int nt = 0; nt < 4; ++nt)
                bf[nt] = *reinterpret_cast<const bf16x8*>(
                    &Bs[(brow + nt * 16) * LDSW + kk + koff]);
#pragma unroll
            for (int mt = 0; mt < 4; ++mt)
#pragma unroll
                for (int nt = 0; nt < 4; ++nt)
                    acc[mt][nt] = __builtin_amdgcn_mfma_f32_16x16x32_bf16(
                        af[mt], bf[nt], acc[mt][nt], 0, 0, 0);
        }
        __syncthreads();
    }

#pragma unroll
    for (int nt = 0; nt < 4; ++nt) {
        const int col = n0 + wn * 64 + nt * 16 + (lane & 15);
        const float bv = bias[col];
#pragma unroll
        for (int mt = 0; mt < 4; ++mt) {
            const int rbase = m0 + wm * 64 + mt * 16 + (lane >> 4) * 4;
#pragma unroll
            for (int r = 0; r < 4; ++r)
                C[(size_t)(rbase + r) * HH + col] = acc[mt][nt][r] + bv;
        }
    }
}

// ---------------------------------------------------------------------------
// Kernel 1 (fallback): fp32 VALU GEMM
// ---------------------------------------------------------------------------
#define BM 128
#define BN 128
#define BK 8

__global__ __launch_bounds__(256, 2) void gemm_xw(
    const float* __restrict__ A,
    const float* __restrict__ B,
    const float* __restrict__ bias,
    float* __restrict__ C)
{
    __shared__ float As[BK][BM];
    __shared__ float Bs[BK][BN];

    const int tid  = threadIdx.x;
    const int tm   = tid >> 4;
    const int tn   = tid & 15;
    const int row0 = blockIdx.x * BM;
    const int col0 = blockIdx.y * BN;

    const int ar = tid >> 1;
    const int ac = (tid & 1) * 4;
    const int br = tid >> 5;
    const int bc = (tid & 31) * 4;

    float acc[8][8];
#pragma unroll
    for (int i = 0; i < 8; ++i)
#pragma unroll
        for (int j = 0; j < 8; ++j) acc[i][j] = 0.f;

    for (int k0 = 0; k0 < DD; k0 += BK) {
        float4 av = *reinterpret_cast<const float4*>(
            &A[(size_t)(row0 + ar) * DD + k0 + ac]);
        float4 bv = *reinterpret_cast<const float4*>(
            &B[(size_t)(k0 + br) * HH + col0 + bc]);

        As[ac + 0][ar] = av.x;
        As[ac + 1][ar] = av.y;
        As[ac + 2][ar] = av.z;
        As[ac + 3][ar] = av.w;
        *reinterpret_cast<float4*>(&Bs[br][bc]) = bv;
        __syncthreads();

#pragma unroll
        for (int kk = 0; kk < BK; ++kk) {
            float a[8], b[8];
            *reinterpret_cast<float4*>(&a[0]) =
                *reinterpret_cast<const float4*>(&As[kk][tm * 8]);
            *reinterpret_cast<float4*>(&a[4]) =
                *reinterpret_cast<const float4*>(&As[kk][tm * 8 + 4]);
            *reinterpret_cast<float4*>(&b[0]) =
                *reinterpret_cast<const float4*>(&Bs[kk][tn * 8]);
            *reinterpret_cast<float4*>(&b[4]) =
                *reinterpret_cast<const float4*>(&Bs[kk][tn * 8 + 4]);
#pragma unroll
            for (int i = 0; i < 8; ++i)
#pragma unroll
                for (int j = 0; j < 8; ++j)
                    acc[i][j] = fmaf(a[i], b[j], acc[i][j]);
        }
        __syncthreads();
    }

#pragma unroll
    for (int i = 0; i < 8; ++i) {
        const int row = row0 + tm * 8 + i;
#pragma unroll
        for (int j = 0; j < 8; j += 4) {
            const int col = col0 + tn * 8 + j;
            float4 o;
            o.x = acc[i][j + 0] + bias[col + 0];
            o.y = acc[i][j + 1] + bias[col + 1];
            o.z = acc[i][j + 2] + bias[col + 2];
            o.w = acc[i][j + 3] + bias[col + 3];
            *reinterpret_cast<float4*>(&C[(size_t)row * HH + col]) = o;
        }
    }
}

// ---------------------------------------------------------------------------
// Kernel 2: grouped scan (r4/r8 structure) + XCC_ID rendezvous + L2-ATOMIC
// mirror fast path — EXACT round-11 build (measured best: scan 1290us).
// Publish: global_atomic_swap_x2 (serialization-point RMW) first; poll:
// returning atomic_add_x2(0) alternated with relaxed agent truth load,
// no sleep. Tag/parity/replay safety as established.
// ---------------------------------------------------------------------------
__global__ __launch_bounds__(1024, 4) void rnn_scan_l2a(
    const float* __restrict__ Wh,     // (H, H) fp32 row-major
    const float* __restrict__ h0,     // (N, H)
    float* __restrict__ out,          // (N, T, H): in = xw, out = h
    uint64_t* __restrict__ truth,     // [NB][2][HH] agent-scope packets
    uint64_t* __restrict__ mirror,    // [NB][2][HH] RMW packets
    int* __restrict__ meta)           // [16] rendezvous counters (pre-zeroed)
{
    __shared__ __align__(16) uint32_t hp[2][HH / 2];
    __shared__ float partial[16][128];
    __shared__ int sh_batch, sh_role, sh_fast;

    const int tid = threadIdx.x;

    // ---- rendezvous: physical-XCD-aware group assignment ----
    int xcd_raw;
    asm volatile("s_getreg_b32 %0, hwreg(HW_REG_XCC_ID)" : "=s"(xcd_raw));
    const int xcd = xcd_raw & 7;

    if (tid == 0) {
        int pos = __hip_atomic_fetch_add(&meta[xcd], 1, __ATOMIC_RELAXED,
                                         __HIP_MEMORY_SCOPE_AGENT);
        __hip_atomic_fetch_add(&meta[8], 1, __ATOMIC_RELEASE,
                               __HIP_MEMORY_SCOPE_AGENT);
        while (__hip_atomic_load(&meta[8], __ATOMIC_ACQUIRE,
                                 __HIP_MEMORY_SCOPE_AGENT) < 256)
            __builtin_amdgcn_s_sleep(8);
        int c[8];
#pragma unroll
        for (int q = 0; q < 8; ++q)
            c[q] = __hip_atomic_load(&meta[q], __ATOMIC_RELAXED,
                                     __HIP_MEMORY_SCOPE_AGENT);
        int totalfull = 0, basefull = 0, rembase = 0;
#pragma unroll
        for (int q = 0; q < 8; ++q) totalfull += c[q] >> 2;
        for (int q = 0; q < xcd; ++q) {
            basefull += c[q] >> 2;
            rembase  += c[q] & 3;
        }
        const int nf4 = (c[xcd] >> 2) << 2;
        if (pos < nf4) {             // full same-XCD quad -> fast group
            sh_batch = basefull + (pos >> 2);
            sh_role  = pos & 3;
            sh_fast  = 1;
        } else {                     // remainder -> mixed group, agent path
            int ridx = rembase + (pos - nf4);
            sh_batch = totalfull + (ridx >> 2);
            sh_role  = ridx & 3;
            sh_fast  = 0;
        }
    }
    __syncthreads();

    const int n    = sh_batch;
    const int jb   = sh_role << 7;
    const int fast = sh_fast;

    const int w = tid >> 6;            // wave 0..15 -> k slice [w*32,+32)
    const int l = tid & 63;

    // ---- one-time: weight slice -> registers as packed fp16 ----
    uint32_t w0[16], w1[16];
    {
        const float* wc = Wh + (size_t)(w * 32) * HH + jb + l;
#pragma unroll
        for (int p = 0; p < 16; ++p) {
            float e0 = wc[(size_t)(2 * p) * HH];
            float e1 = wc[(size_t)(2 * p + 1) * HH];
            w0[p] = __builtin_bit_cast(uint32_t, __floats2half2_rn(e0, e1));
            float f0 = wc[(size_t)(2 * p) * HH + 64];
            float f1 = wc[(size_t)(2 * p + 1) * HH + 64];
            w1[p] = __builtin_bit_cast(uint32_t, __floats2half2_rn(f0, f1));
        }
    }

    if (tid < HH)
        ((__half*)hp[0])[tid] = __float2half(h0[(size_t)n * HH + tid]);
    __syncthreads();

    float* outn = out + (size_t)n * TT * HH;
    uint64_t* tru = truth  + (size_t)n * 2 * HH;
    uint64_t* mir = mirror + (size_t)n * 2 * HH;

    const int rcol = (jb + 128 + (tid - 128)) & (HH - 1);

    int cur = 0;
    for (int t = 0; t < TT; ++t) {
        const uint32_t T = (uint32_t)(t + 1);
        const int slot = (int)(T & 1u);

        float xw_r = 0.f;
        if (tid < 128) xw_r = outn[(size_t)t * HH + jb + tid];

        const uint32_t* hpw = &hp[cur][w * 16];
        float a0 = 0.f, a1 = 0.f, b0 = 0.f, b1 = 0.f;
#pragma unroll
        for (int q = 0; q < 4; ++q) {
            uint4 hv = ((const uint4*)hpw)[q];
            a0 = dot2f(hv.x, w0[4 * q + 0], a0);
            b0 = dot2f(hv.x, w1[4 * q + 0], b0);
            a1 = dot2f(hv.y, w0[4 * q + 1], a1);
            b1 = dot2f(hv.y, w1[4 * q + 1], b1);
            a0 = dot2f(hv.z, w0[4 * q + 2], a0);
            b0 = dot2f(hv.z, w1[4 * q + 2], b0);
            a1 = dot2f(hv.w, w0[4 * q + 3], a1);
            b1 = dot2f(hv.w, w1[4 * q + 3], b1);
        }
        partial[w][l] = a0 + a1;
        partial[w][64 + l] = b0 + b1;
        __syncthreads();                                      // B1

        __half* hpn = (__half*)hp[cur ^ 1];
        if (tid < 128) {
            float s = 0.f;
#pragma unroll
            for (int ww = 0; ww < 16; ++ww) s += partial[ww][tid];
            float h = fast_tanh(s + xw_r);
            uint64_t pk = ((uint64_t)T << 32) |
                          (uint64_t)__builtin_bit_cast(uint32_t, h);
            const int off = slot * HH + jb + tid;
            // publish FIRST (critical path), side-writes after
            if (fast) {   // atomic swap, no sc1 -> serialization point
                asm volatile("global_atomic_swap_x2 %0, %1, off"
                             :: "v"((uint64_t)&mir[off]), "v"(pk) : "memory");
            }
            __hip_atomic_store(&tru[off], pk, __ATOMIC_RELAXED,
                               __HIP_MEMORY_SCOPE_AGENT);
            outn[(size_t)t * HH + jb + tid] = h;
            hpn[jb + tid] = __float2half(h);
        } else if (tid < 512) {
            const int off = slot * HH + rcol;
            uint64_t v;
            if (fast) {
                const uint64_t maddr = (uint64_t)&mir[off];
                const uint64_t zero = 0;
                while (true) {
                    // returning atomic add(0): RMW at the serialization
                    // point, sc0 = return old value. Always fresh.
                    asm volatile(
                        "global_atomic_add_x2 %0, %1, %2, off sc0\n\t"
                        "s_waitcnt vmcnt(0)"
                        : "=v"(v) : "v"(maddr), "v"(zero) : "memory");
                    if ((uint32_t)(v >> 32) == T) break;
                    v = __hip_atomic_load(&tru[off], __ATOMIC_RELAXED,
                                          __HIP_MEMORY_SCOPE_AGENT);
                    if ((uint32_t)(v >> 32) == T) break;
                }
            } else {
                v = __hip_atomic_load(&tru[off], __ATOMIC_RELAXED,
                                      __HIP_MEMORY_SCOPE_AGENT);
                while ((uint32_t)(v >> 32) != T) {
                    __builtin_amdgcn_s_sleep(1);
                    v = __hip_atomic_load(&tru[off], __ATOMIC_RELAXED,
                                          __HIP_MEMORY_SCOPE_AGENT);
                }
            }
            hpn[rcol] = __float2half(__builtin_bit_cast(float, (uint32_t)v));
        }
        __syncthreads();                                      // B2
        cur ^= 1;
    }
}

// ---------------------------------------------------------------------------
// Fallback scan (no workspace needed)
// ---------------------------------------------------------------------------
__global__ __launch_bounds__(512, 2) void rnn_scan_f32(
    const float* __restrict__ Wh,
    const float* __restrict__ h0,
    float* __restrict__ out)
{
    __shared__ float hbuf[2][HH];
    const int n = blockIdx.x;
    const int j = threadIdx.x;

    hbuf[0][j] = h0[(size_t)n * HH + j];
    __syncthreads();

    float* outn = out + (size_t)n * TT * HH;
    const float* __restrict__ wp = Wh + j;

    int cur = 0;
    for (int t = 0; t < TT; ++t) {
        float acc = outn[(size_t)t * HH + j];
        const float* hc = hbuf[cur];
#pragma unroll 4
        for (int k = 0; k < HH; k += 4) {
            float4 hv = *reinterpret_cast<const float4*>(&hc[k]);
            acc = fmaf(hv.x, wp[(size_t)(k + 0) * HH], acc);
            acc = fmaf(hv.y, wp[(size_t)(k + 1) * HH], acc);
            acc = fmaf(hv.z, wp[(size_t)(k + 2) * HH], acc);
            acc = fmaf(hv.w, wp[(size_t)(k + 3) * HH], acc);
        }
        float hn = tanhf(acc);
        outn[(size_t)t * HH + j] = hn;
        hbuf[cur ^ 1][j] = hn;
        cur ^= 1;
        __syncthreads();
    }
}

// ---------------------------------------------------------------------------
extern "C" void kernel_launch(void* const* d_in, const int* in_sizes, int n_in,
                              void* d_out, int out_size, void* d_ws, size_t ws_size,
                              hipStream_t stream) {
    const float* x  = (const float*)d_in[0];   // (N, T, D)
    const float* h0 = (const float*)d_in[1];   // (N, H)
    const float* Wx = (const float*)d_in[2];   // (D, H)
    const float* Wh = (const float*)d_in[3];   // (H, H)
    const float* b  = (const float*)d_in[4];   // (H)
    float* out = (float*)d_out;                // (N, T, H)

    const long   M      = (long)NB * TT;                 // 65536
    const size_t pkt_b  = (size_t)NB * 2 * HH * 8;       // 512 KB per region
    const size_t meta_b = 4096;
    const size_t wt_b   = (size_t)HH * DD * 2;           // 512 KB
    const size_t xb_b   = (size_t)M * DD * 2;            // 64 MB

    const size_t off_mir  = pkt_b;
    const size_t off_meta = 2 * pkt_b;
    const size_t off_wt   = 2 * pkt_b + meta_b;
    const size_t off_xb   = off_wt + wt_b;
    const size_t need_all = off_xb + xb_b;
    const size_t need_mid = 2 * pkt_b + meta_b;

    if (ws_size >= need_all) {
        uint64_t*       truth  = (uint64_t*)d_ws;
        uint64_t*       mirror = (uint64_t*)((char*)d_ws + off_mir);
        int*            meta   = (int*)((char*)d_ws + off_meta);
        unsigned short* Wt     = (unsigned short*)((char*)d_ws + off_wt);
        unsigned short* xb     = (unsigned short*)((char*)d_ws + off_xb);

        conv_x<<<2048, 256, 0, stream>>>(x, xb, M * DD);
        conv_wt<<<HH, 64, 0, stream>>>(Wx, Wt);
        dim3 gg(M / GBM, HH / GBN);
        gemm_bf16<<<gg, 256, 0, stream>>>(xb, Wt, b, out);
        hipMemsetAsync(meta, 0, 64, stream);   // rendezvous counters
        rnn_scan_l2a<<<256, 1024, 0, stream>>>(Wh, h0, out, truth, mirror, meta);
    } else if (ws_size >= need_mid) {
        uint64_t* truth  = (uint64_t*)d_ws;
        uint64_t* mirror = (uint64_t*)((char*)d_ws + off_mir);
        int*      meta   = (int*)((char*)d_ws + off_meta);
        dim3 g1(M / BM, HH / BN);
        gemm_xw<<<g1, 256, 0, stream>>>(x, Wx, b, out);
        hipMemsetAsync(meta, 0, 64, stream);
        rnn_scan_l2a<<<256, 1024, 0, stream>>>(Wh, h0, out, truth, mirror, meta);
    } else {
        dim3 g1(M / BM, HH / BN);
        gemm_xw<<<g1, 256, 0, stream>>>(x, Wx, b, out);
        rnn_scan_f32<<<NB, 512, 0, stream>>>(Wh, h0, out);
    }
}